// Round 4
// baseline (1232.520 us; speedup 1.0000x reference)
//
#include <hip/hip_runtime.h>

typedef __attribute__((ext_vector_type(8))) short bf16x8;
typedef __attribute__((ext_vector_type(4))) float f32x4;
typedef __attribute__((ext_vector_type(2))) unsigned u32x2;

#define MFMA(a, b, c) __builtin_amdgcn_mfma_f32_16x16x32_bf16((a), (b), (c), 0, 0, 0)
#define Q_SCALE 0.17677669529663687f /* 32^-0.5 */
// XOR swizzle for 256B-row token-major tiles (XS / AO): 2-way banking max.
// Swizzle bits live at address bits 4-6 -> compute full address BEFORE XOR.
#define SWZ(t) ((((t) >> 2) & 7) << 4)

__device__ __forceinline__ short f2bf(float f) {
  union { float f; unsigned u; } c; c.f = f;
  unsigned u = c.u;
  return (short)((u + 0x7FFFu + ((u >> 16) & 1u)) >> 16);  // RNE
}

__device__ __forceinline__ unsigned cvtpk(float lo, float hi) {
  unsigned r;
  asm("v_cvt_pk_bf16_f32 %0, %1, %2" : "=v"(r) : "v"(lo), "v"(hi));
  return r;
}

// v_permlane32_swap_b32: a' = [a.lanes0-31 | b.lanes0-31], b' = [a.hi | b.hi]
__device__ __forceinline__ void pl32swap(unsigned& a, unsigned& b) {
  asm volatile("v_permlane32_swap_b32 %0, %1" : "+v"(a), "+v"(b));
}
// lane l -> lane l^16 within each 32-lane half (bank-conflict-free)
__device__ __forceinline__ unsigned swz16(unsigned x) {
  return (unsigned)__builtin_amdgcn_ds_swizzle((int)x, 0x401F);
}

// C-frag -> A/B-frag lane exchange (intra-wave), conflict-free version.
// pa* = dwords of k-tile 0 (4 bf16 in reg-run order), pb* = k-tile 1.
// dest lane (llo,lhi) gets 8 consecutive k at k0 = lhi*8 from tile (lhi>>1);
// odd = lhi&1. Derivation (verified per-lhi): with r0=[pa_lo|pb_lo],
// r1=[pa_hi|pb_hi]:  u[0]=odd?swz16(r1):r0,  u[2]=odd?r1:swz16(r0).
__device__ __forceinline__ bf16x8 xch2(unsigned pa0, unsigned pa1,
                                       unsigned pb0, unsigned pb1, int odd) {
  unsigned a0 = pa0, b0 = pb0, a1 = pa1, b1 = pb1;
  pl32swap(a0, b0);  // a0 = r0, b0 = r1  (pair 0)
  pl32swap(a1, b1);  // a1 = r0, b1 = r1  (pair 1)
  unsigned s0 = swz16(b0), s1 = swz16(b1);  // swz16(r1)
  unsigned t0 = swz16(a0), t1 = swz16(a1);  // swz16(r0)
  union { unsigned u[4]; bf16x8 v; } r;
  r.u[0] = odd ? s0 : a0;
  r.u[1] = odd ? s1 : a1;
  r.u[2] = odd ? b0 : t0;
  r.u[3] = odd ? b1 : t1;
  return r.v;
}

// ---------------------------------------------------------------------------
// prep: bf16 weights (Q rows pre-scaled), scaled qkv bias, bias table gathered
// in TRANSPOSED C-frag order: rows = key j, cols = query i.
// ---------------------------------------------------------------------------
__global__ void prep_kernel(const float* __restrict__ qkv_w,
                            const float* __restrict__ qkv_b,
                            const float* __restrict__ proj_w,
                            const float* __restrict__ tbl,
                            const int* __restrict__ ridx,
                            short* __restrict__ wq, short* __restrict__ wp,
                            float* __restrict__ qb, float* __restrict__ bfr) {
  const int stride = gridDim.x * blockDim.x;
  const int tid = blockIdx.x * blockDim.x + threadIdx.x;
  for (int i = tid; i < 384 * 128; i += stride)
    wq[i] = f2bf(qkv_w[i] * (i < 128 * 128 ? Q_SCALE : 1.f));
  for (int i = tid; i < 128 * 128; i += stride) wp[i] = f2bf(proj_w[i]);
  for (int i = tid; i < 384; i += stride)
    qb[i] = qkv_b[i] * (i < 128 ? Q_SCALE : 1.f);
  for (int i = tid; i < 4 * 64 * 64; i += stride) {
    int reg = i & 3, it = (i >> 2) & 3, jt = (i >> 4) & 3;
    int l = (i >> 6) & 63, h = i >> 12;
    int qi = it * 16 + (l & 15);            // query (column)
    int kj = jt * 16 + (l >> 4) * 4 + reg;  // key (row)
    bfr[i] = tbl[ridx[qi * 64 + kj] * 4 + h];
  }
}

// ---------------------------------------------------------------------------
// fused window attention, register-resident QKV/P (wave = head).
// LDS: single 16 KB token-major [64][128] bf16 region, XOR-swizzled:
//   phase 0/1: XS (x tile);  phase 4/6: AO (attn output, pre-proj).
// 3 barriers; 6 blocks/CU (96 KB LDS, VGPR cap 85 vs 84 used).
// ---------------------------------------------------------------------------
__global__ __launch_bounds__(256, 6) void winattn_kernel(
    const float* __restrict__ x, const float* __restrict__ proj_b,
    const short* __restrict__ wq, const short* __restrict__ wp,
    const float* __restrict__ qb, const float* __restrict__ bfr,
    float* __restrict__ out) {
  __shared__ __align__(16) char lds[16384];

  const int tid = threadIdx.x;
  const int w = tid >> 6;  // wave id == head
  const int l = tid & 63;
  const int llo = l & 15, lhi = l >> 4;
  const int odd = lhi & 1;

  // XCD-bijective swizzle (8192 % 8 == 0)
  const int bid = blockIdx.x;
  const int wid = (bid & 7) * 1024 + (bid >> 3);
  const int b = wid >> 10;
  const int wy = (wid >> 5) & 31, wx = wid & 31;
  const int y0 = wy * 8, x0 = wx * 8;

  // ---- Phase 0: global x (f32) -> XS bf16 [token][channel], swizzled
  const float* xb = x + (size_t)b * 128 * 65536;
#pragma unroll
  for (int k = 0; k < 8; ++k) {
    int u = tid + k * 256;
    int c = u >> 4, i = (u >> 1) & 7, j4 = u & 1;
    f32x4 v4 = *(const f32x4*)(xb + (size_t)c * 65536 + (y0 + i) * 256 + x0 + j4 * 4);
    int t0 = i * 8 + j4 * 4;
    int base = (t0 * 256 + c * 2) ^ SWZ(t0);  // t0..t0+3 share swizzle bits
    *(short*)(lds + base + 0) = f2bf(v4[0]);
    *(short*)(lds + base + 256) = f2bf(v4[1]);
    *(short*)(lds + base + 512) = f2bf(v4[2]);
    *(short*)(lds + base + 768) = f2bf(v4[3]);
  }
  __syncthreads();

  // ---- Phase 1: QKV GEMM, outputs packed bf16 in registers.
  // g 0,1 = Q tiles (C[o][t]); 2,3 = K tiles (C[o][t]); 4,5 = V tiles (C[t][d])
  unsigned pkq[2][4][2], pkk[2][4][2], pkv[2][4][2];
#pragma unroll
  for (int grp = 0; grp < 2; ++grp) {
    bf16x8 wf[3][4];
    f32x4 qb4[3];
    float bv[3];
#pragma unroll
    for (int gi = 0; gi < 3; ++gi) {
      const int g = grp * 3 + gi;
      const int rowbase = (g >> 1) * 128 + w * 32 + (g & 1) * 16;
#pragma unroll
      for (int ks = 0; ks < 4; ++ks)
        wf[gi][ks] = *(const bf16x8*)(wq + (rowbase + llo) * 128 + ks * 32 + lhi * 8);
      if (g < 4)
        qb4[gi] = *(const f32x4*)(qb + rowbase + lhi * 4);
      else
        bv[gi] = qb[rowbase + llo];
    }
#pragma unroll
    for (int tt = 0; tt < 4; ++tt) {
      bf16x8 xf[4];
      const int t = tt * 16 + llo;
#pragma unroll
      for (int ks = 0; ks < 4; ++ks)
        xf[ks] = *(const bf16x8*)(lds + ((t * 256 + ks * 64 + lhi * 16) ^ SWZ(t)));
#pragma unroll
      for (int gi = 0; gi < 3; ++gi) {
        const int g = grp * 3 + gi;
        f32x4 acc = {0.f, 0.f, 0.f, 0.f};
        if (g < 4) {
#pragma unroll
          for (int ks = 0; ks < 4; ++ks) acc = MFMA(wf[gi][ks], xf[ks], acc);
          unsigned d0 = cvtpk(acc[0] + qb4[gi][0], acc[1] + qb4[gi][1]);
          unsigned d1 = cvtpk(acc[2] + qb4[gi][2], acc[3] + qb4[gi][3]);
          if (g < 2) { pkq[g][tt][0] = d0; pkq[g][tt][1] = d1; }
          else       { pkk[g - 2][tt][0] = d0; pkk[g - 2][tt][1] = d1; }
        } else {
#pragma unroll
          for (int ks = 0; ks < 4; ++ks) acc = MFMA(xf[ks], wf[gi][ks], acc);
          pkv[g - 4][tt][0] = cvtpk(acc[0] + bv[gi], acc[1] + bv[gi]);
          pkv[g - 4][tt][1] = cvtpk(acc[2] + bv[gi], acc[3] + bv[gi]);
        }
      }
    }
  }
  __syncthreads();  // XS dead -> AO region writable later

  // ---- Build K A-frags (rows = key token over d) and V A-frags (rows = d over j)
  bf16x8 kf[4], va[2][2];
#pragma unroll
  for (int jt = 0; jt < 4; ++jt)
    kf[jt] = xch2(pkk[0][jt][0], pkk[0][jt][1], pkk[1][jt][0], pkk[1][jt][1], odd);
#pragma unroll
  for (int vt = 0; vt < 2; ++vt)
#pragma unroll
    for (int ks = 0; ks < 2; ++ks)
      va[vt][ks] = xch2(pkv[vt][2 * ks][0], pkv[vt][2 * ks][1],
                        pkv[vt][2 * ks + 1][0], pkv[vt][2 * ks + 1][1], odd);

  // ---- Phases 2-4 fused, streamed per query tile `it`
  const f32x4* bias4 = (const f32x4*)bfr + ((w * 64 + l) << 4);
#pragma unroll
  for (int it = 0; it < 4; ++it) {
    bf16x8 qf = xch2(pkq[0][it][0], pkq[0][it][1], pkq[1][it][0], pkq[1][it][1], odd);
    f32x4 dots[4];
#pragma unroll
    for (int jt = 0; jt < 4; ++jt) {
      dots[jt] = bias4[jt * 4 + it];            // bias preloaded as accumulator
      dots[jt] = MFMA(kf[jt], qf, dots[jt]);    // C[j][i]: rows=key, cols=query
    }
    // softmax over key axis: 16 lane-local values + 2 cross-lhi shfls
    float m = dots[0][0];
#pragma unroll
    for (int jt = 0; jt < 4; ++jt)
#pragma unroll
      for (int r = 0; r < 4; ++r) m = fmaxf(m, dots[jt][r]);
    m = fmaxf(m, __shfl_xor(m, 16));
    m = fmaxf(m, __shfl_xor(m, 32));
    float p[4][4];
    float s = 0.f;
#pragma unroll
    for (int jt = 0; jt < 4; ++jt)
#pragma unroll
      for (int r = 0; r < 4; ++r) {
        p[jt][r] = __expf(dots[jt][r] - m);
        s += p[jt][r];
      }
    s += __shfl_xor(s, 16);
    s += __shfl_xor(s, 32);
    const float inv = 1.f / s;
    unsigned pk[4][2];
#pragma unroll
    for (int jt = 0; jt < 4; ++jt) {
      pk[jt][0] = cvtpk(p[jt][0], p[jt][1]);
      pk[jt][1] = cvtpk(p[jt][2], p[jt][3]);
    }
    bf16x8 pb0 = xch2(pk[0][0], pk[0][1], pk[1][0], pk[1][1], odd);
    bf16x8 pb1 = xch2(pk[2][0], pk[2][1], pk[3][0], pk[3][1], odd);
    // PV: C[d][t] (rows = d, cols = query token)
    f32x4 o0 = {0.f, 0.f, 0.f, 0.f}, o1 = {0.f, 0.f, 0.f, 0.f};
    o0 = MFMA(va[0][0], pb0, o0);
    o0 = MFMA(va[0][1], pb1, o0);
    o1 = MFMA(va[1][0], pb0, o1);
    o1 = MFMA(va[1][1], pb1, o1);
    // normalize + write AO[t][c] (c = head*32 + d), packed b64, swizzled.
    // Full byte address computed BEFORE the XOR (bit 5 is a swizzle bit).
    const int t = it * 16 + llo;
    const int byte0 = (t * 256 + (w * 32 + lhi * 4) * 2) ^ SWZ(t);
    const int byte1 = (t * 256 + (w * 32 + 16 + lhi * 4) * 2) ^ SWZ(t);
    u32x2 w0, w1;
    w0.x = cvtpk(o0[0] * inv, o0[1] * inv);
    w0.y = cvtpk(o0[2] * inv, o0[3] * inv);
    w1.x = cvtpk(o1[0] * inv, o1[1] * inv);
    w1.y = cvtpk(o1[2] * inv, o1[3] * inv);
    *(u32x2*)(lds + byte0) = w0;
    *(u32x2*)(lds + byte1) = w1;
  }

  // ---- Phase 6: proj. A = wp rows (och over c), B = AO rows (t over c).
  bf16x8 wpf[2][4];
  f32x4 pb4[2];
#pragma unroll
  for (int ot = 0; ot < 2; ++ot) {
#pragma unroll
    for (int ks = 0; ks < 4; ++ks)
      wpf[ot][ks] = *(const bf16x8*)(wp + (w * 32 + ot * 16 + llo) * 128 + ks * 32 + lhi * 8);
    pb4[ot] = *(const f32x4*)(proj_b + w * 32 + ot * 16 + lhi * 4);
  }
  __syncthreads();  // AO complete

  float* ob = out + (size_t)b * 128 * 65536;
#pragma unroll
  for (int it = 0; it < 4; ++it) {
    const int t = it * 16 + llo;
    bf16x8 af[4];
#pragma unroll
    for (int ks = 0; ks < 4; ++ks)
      af[ks] = *(const bf16x8*)(lds + ((t * 256 + ks * 64 + lhi * 16) ^ SWZ(t)));
#pragma unroll
    for (int ot = 0; ot < 2; ++ot) {
      f32x4 acc = {0.f, 0.f, 0.f, 0.f};
#pragma unroll
      for (int ks = 0; ks < 4; ++ks) acc = MFMA(wpf[ot][ks], af[ks], acc);
#pragma unroll
      for (int r = 0; r < 4; ++r) {
        const int ch = w * 32 + ot * 16 + lhi * 4 + r;
        ob[(size_t)ch * 65536 + (y0 + (t >> 3)) * 256 + x0 + (t & 7)] =
            acc[r] + pb4[ot][r];
      }
    }
  }
}

extern "C" void kernel_launch(void* const* d_in, const int* in_sizes, int n_in,
                              void* d_out, int out_size, void* d_ws, size_t ws_size,
                              hipStream_t stream) {
  const float* x = (const float*)d_in[0];
  const float* qkv_w = (const float*)d_in[1];
  const float* qkv_b = (const float*)d_in[2];
  const float* proj_w = (const float*)d_in[3];
  const float* proj_b = (const float*)d_in[4];
  const float* tbl = (const float*)d_in[5];
  const int* ridx = (const int*)d_in[6];
  float* out = (float*)d_out;

  char* ws = (char*)d_ws;
  short* wq = (short*)ws;                    //      0 .. 98304: qkv_w bf16 (Q pre-scaled)
  short* wp = (short*)(ws + 98304);          //  98304 ..131072: proj_w bf16
  float* qb = (float*)(ws + 131072);         // 131072 ..132608: scaled qkv_b f32
  float* bfr = (float*)(ws + 132608);        // 132608 ..198144: bias, transposed frag order

  prep_kernel<<<64, 256, 0, stream>>>(qkv_w, qkv_b, proj_w, tbl, ridx, wq, wp, qb, bfr);
  winattn_kernel<<<8192, 256, 0, stream>>>(x, proj_b, wq, wp, qb, bfr, out);
}

// Round 5
// 507.116 us; speedup vs baseline: 2.4304x; 2.4304x over previous
//
#include <hip/hip_runtime.h>

typedef __attribute__((ext_vector_type(8))) short bf16x8;
typedef __attribute__((ext_vector_type(4))) float f32x4;
typedef __attribute__((ext_vector_type(2))) unsigned u32x2;

#define MFMA(a, b, c) __builtin_amdgcn_mfma_f32_16x16x32_bf16((a), (b), (c), 0, 0, 0)
#define Q_SCALE 0.17677669529663687f /* 32^-0.5 */
// XOR swizzle for 256B-row token-major tiles (XS / AO): 2-way banking max.
// Swizzle bits live at address bits 4-6 -> compute full address BEFORE XOR.
#define SWZ(t) ((((t) >> 2) & 7) << 4)

__device__ __forceinline__ short f2bf(float f) {
  union { float f; unsigned u; } c; c.f = f;
  unsigned u = c.u;
  return (short)((u + 0x7FFFu + ((u >> 16) & 1u)) >> 16);  // RNE
}

__device__ __forceinline__ unsigned cvtpk(float lo, float hi) {
  unsigned r;
  asm("v_cvt_pk_bf16_f32 %0, %1, %2" : "=v"(r) : "v"(lo), "v"(hi));
  return r;
}

// v_permlane32_swap_b32: a' = [a.lanes0-31 | b.lanes0-31], b' = [a.hi | b.hi]
__device__ __forceinline__ void pl32swap(unsigned& a, unsigned& b) {
  asm volatile("v_permlane32_swap_b32 %0, %1" : "+v"(a), "+v"(b));
}
// lane l -> lane l^16 within each 32-lane half (bank-conflict-free)
__device__ __forceinline__ unsigned swz16(unsigned x) {
  return (unsigned)__builtin_amdgcn_ds_swizzle((int)x, 0x401F);
}

// C-frag -> A/B-frag lane exchange (intra-wave), conflict-free version.
// pa* = dwords of k-tile 0 (4 bf16 in reg-run order), pb* = k-tile 1.
// dest lane (llo,lhi) gets 8 consecutive k at k0 = lhi*8 from tile (lhi>>1);
// odd = lhi&1. With r0=[pa_lo|pb_lo], r1=[pa_hi|pb_hi]:
//   u[0]=odd?swz16(r1):r0,  u[2]=odd?r1:swz16(r0)  (same for pair 1).
__device__ __forceinline__ bf16x8 xch2(unsigned pa0, unsigned pa1,
                                       unsigned pb0, unsigned pb1, int odd) {
  unsigned a0 = pa0, b0 = pb0, a1 = pa1, b1 = pb1;
  pl32swap(a0, b0);
  pl32swap(a1, b1);
  unsigned s0 = swz16(b0), s1 = swz16(b1);
  unsigned t0 = swz16(a0), t1 = swz16(a1);
  union { unsigned u[4]; bf16x8 v; } r;
  r.u[0] = odd ? s0 : a0;
  r.u[1] = odd ? s1 : a1;
  r.u[2] = odd ? b0 : t0;
  r.u[3] = odd ? b1 : t1;
  return r.v;
}

// ---------------------------------------------------------------------------
// prep: bf16 weights (Q rows pre-scaled), scaled qkv bias, bias table gathered
// in TRANSPOSED C-frag order: rows = key j, cols = query i.
// ---------------------------------------------------------------------------
__global__ void prep_kernel(const float* __restrict__ qkv_w,
                            const float* __restrict__ qkv_b,
                            const float* __restrict__ proj_w,
                            const float* __restrict__ tbl,
                            const int* __restrict__ ridx,
                            short* __restrict__ wq, short* __restrict__ wp,
                            float* __restrict__ qb, float* __restrict__ bfr) {
  const int stride = gridDim.x * blockDim.x;
  const int tid = blockIdx.x * blockDim.x + threadIdx.x;
  for (int i = tid; i < 384 * 128; i += stride)
    wq[i] = f2bf(qkv_w[i] * (i < 128 * 128 ? Q_SCALE : 1.f));
  for (int i = tid; i < 128 * 128; i += stride) wp[i] = f2bf(proj_w[i]);
  for (int i = tid; i < 384; i += stride)
    qb[i] = qkv_b[i] * (i < 128 ? Q_SCALE : 1.f);
  for (int i = tid; i < 4 * 64 * 64; i += stride) {
    int reg = i & 3, it = (i >> 2) & 3, jt = (i >> 4) & 3;
    int l = (i >> 6) & 63, h = i >> 12;
    int qi = it * 16 + (l & 15);            // query (column)
    int kj = jt * 16 + (l >> 4) * 4 + reg;  // key (row)
    bfr[i] = tbl[ridx[qi * 64 + kj] * 4 + h];
  }
}

// ---------------------------------------------------------------------------
// fused window attention, register-resident QKV/P (wave = head).
// LDS: single 16 KB token-major [64][128] bf16 region, XOR-swizzled:
//   phase 0/1: XS (x tile);  phase 4/6: AO (attn output, pre-proj).
// 3 barriers. launch_bounds(256,4): VGPR cap 128 >> 84 needed -> no spill
// (the (256,6) cap of 85 vs 84 needed caused catastrophic spills in R4).
// ---------------------------------------------------------------------------
__global__ __launch_bounds__(256, 4) void winattn_kernel(
    const float* __restrict__ x, const float* __restrict__ proj_b,
    const short* __restrict__ wq, const short* __restrict__ wp,
    const float* __restrict__ qb, const float* __restrict__ bfr,
    float* __restrict__ out) {
  __shared__ __align__(16) char lds[16384];

  const int tid = threadIdx.x;
  const int w = tid >> 6;  // wave id == head
  const int l = tid & 63;
  const int llo = l & 15, lhi = l >> 4;
  const int odd = lhi & 1;

  // XCD-bijective swizzle (8192 % 8 == 0)
  const int bid = blockIdx.x;
  const int wid = (bid & 7) * 1024 + (bid >> 3);
  const int b = wid >> 10;
  const int wy = (wid >> 5) & 31, wx = wid & 31;
  const int y0 = wy * 8, x0 = wx * 8;

  // ---- Phase 0: global x (f32) -> XS bf16 [token][channel], swizzled
  const float* xb = x + (size_t)b * 128 * 65536;
#pragma unroll
  for (int k = 0; k < 8; ++k) {
    int u = tid + k * 256;
    int c = u >> 4, i = (u >> 1) & 7, j4 = u & 1;
    f32x4 v4 = *(const f32x4*)(xb + (size_t)c * 65536 + (y0 + i) * 256 + x0 + j4 * 4);
    int t0 = i * 8 + j4 * 4;
    int base = (t0 * 256 + c * 2) ^ SWZ(t0);  // t0..t0+3 share swizzle bits
    *(short*)(lds + base + 0) = f2bf(v4[0]);
    *(short*)(lds + base + 256) = f2bf(v4[1]);
    *(short*)(lds + base + 512) = f2bf(v4[2]);
    *(short*)(lds + base + 768) = f2bf(v4[3]);
  }
  __syncthreads();

  // ---- Phase 1: QKV GEMM, outputs packed bf16 in registers.
  // g 0,1 = Q tiles (C[o][t]); 2,3 = K tiles (C[o][t]); 4,5 = V tiles (C[t][d])
  unsigned pkq[2][4][2], pkk[2][4][2], pkv[2][4][2];
#pragma unroll
  for (int grp = 0; grp < 2; ++grp) {
    bf16x8 wf[3][4];
    f32x4 qb4[3];
    float bv[3];
#pragma unroll
    for (int gi = 0; gi < 3; ++gi) {
      const int g = grp * 3 + gi;
      const int rowbase = (g >> 1) * 128 + w * 32 + (g & 1) * 16;
#pragma unroll
      for (int ks = 0; ks < 4; ++ks)
        wf[gi][ks] = *(const bf16x8*)(wq + (rowbase + llo) * 128 + ks * 32 + lhi * 8);
      if (g < 4)
        qb4[gi] = *(const f32x4*)(qb + rowbase + lhi * 4);
      else
        bv[gi] = qb[rowbase + llo];
    }
#pragma unroll
    for (int tt = 0; tt < 4; ++tt) {
      bf16x8 xf[4];
      const int t = tt * 16 + llo;
#pragma unroll
      for (int ks = 0; ks < 4; ++ks)
        xf[ks] = *(const bf16x8*)(lds + ((t * 256 + ks * 64 + lhi * 16) ^ SWZ(t)));
#pragma unroll
      for (int gi = 0; gi < 3; ++gi) {
        const int g = grp * 3 + gi;
        f32x4 acc = {0.f, 0.f, 0.f, 0.f};
        if (g < 4) {
#pragma unroll
          for (int ks = 0; ks < 4; ++ks) acc = MFMA(wf[gi][ks], xf[ks], acc);
          unsigned d0 = cvtpk(acc[0] + qb4[gi][0], acc[1] + qb4[gi][1]);
          unsigned d1 = cvtpk(acc[2] + qb4[gi][2], acc[3] + qb4[gi][3]);
          if (g < 2) { pkq[g][tt][0] = d0; pkq[g][tt][1] = d1; }
          else       { pkk[g - 2][tt][0] = d0; pkk[g - 2][tt][1] = d1; }
        } else {
#pragma unroll
          for (int ks = 0; ks < 4; ++ks) acc = MFMA(xf[ks], wf[gi][ks], acc);
          pkv[g - 4][tt][0] = cvtpk(acc[0] + bv[gi], acc[1] + bv[gi]);
          pkv[g - 4][tt][1] = cvtpk(acc[2] + bv[gi], acc[3] + bv[gi]);
        }
      }
    }
  }
  __syncthreads();  // XS dead -> AO region writable later

  // ---- Build K A-frags (rows = key token over d) and V A-frags (rows = d over j)
  bf16x8 kf[4], va[2][2];
#pragma unroll
  for (int jt = 0; jt < 4; ++jt)
    kf[jt] = xch2(pkk[0][jt][0], pkk[0][jt][1], pkk[1][jt][0], pkk[1][jt][1], odd);
#pragma unroll
  for (int vt = 0; vt < 2; ++vt)
#pragma unroll
    for (int ks = 0; ks < 2; ++ks)
      va[vt][ks] = xch2(pkv[vt][2 * ks][0], pkv[vt][2 * ks][1],
                        pkv[vt][2 * ks + 1][0], pkv[vt][2 * ks + 1][1], odd);

  // ---- Phases 2-4 fused, streamed per query tile `it`
  const f32x4* bias4 = (const f32x4*)bfr + ((w * 64 + l) << 4);
#pragma unroll
  for (int it = 0; it < 4; ++it) {
    bf16x8 qf = xch2(pkq[0][it][0], pkq[0][it][1], pkq[1][it][0], pkq[1][it][1], odd);
    f32x4 dots[4];
#pragma unroll
    for (int jt = 0; jt < 4; ++jt) {
      dots[jt] = bias4[jt * 4 + it];            // bias preloaded as accumulator
      dots[jt] = MFMA(kf[jt], qf, dots[jt]);    // C[j][i]: rows=key, cols=query
    }
    // softmax over key axis: 16 lane-local values + 2 cross-lhi shfls
    float m = dots[0][0];
#pragma unroll
    for (int jt = 0; jt < 4; ++jt)
#pragma unroll
      for (int r = 0; r < 4; ++r) m = fmaxf(m, dots[jt][r]);
    m = fmaxf(m, __shfl_xor(m, 16));
    m = fmaxf(m, __shfl_xor(m, 32));
    float p[4][4];
    float s = 0.f;
#pragma unroll
    for (int jt = 0; jt < 4; ++jt)
#pragma unroll
      for (int r = 0; r < 4; ++r) {
        p[jt][r] = __expf(dots[jt][r] - m);
        s += p[jt][r];
      }
    s += __shfl_xor(s, 16);
    s += __shfl_xor(s, 32);
    const float inv = 1.f / s;
    unsigned pk[4][2];
#pragma unroll
    for (int jt = 0; jt < 4; ++jt) {
      pk[jt][0] = cvtpk(p[jt][0], p[jt][1]);
      pk[jt][1] = cvtpk(p[jt][2], p[jt][3]);
    }
    bf16x8 pb0 = xch2(pk[0][0], pk[0][1], pk[1][0], pk[1][1], odd);
    bf16x8 pb1 = xch2(pk[2][0], pk[2][1], pk[3][0], pk[3][1], odd);
    // PV: C[d][t] (rows = d, cols = query token)
    f32x4 o0 = {0.f, 0.f, 0.f, 0.f}, o1 = {0.f, 0.f, 0.f, 0.f};
    o0 = MFMA(va[0][0], pb0, o0);
    o0 = MFMA(va[0][1], pb1, o0);
    o1 = MFMA(va[1][0], pb0, o1);
    o1 = MFMA(va[1][1], pb1, o1);
    // normalize + write AO[t][c] (c = head*32 + d), packed b64, swizzled.
    // Full byte address computed BEFORE the XOR (bit 5 is a swizzle bit).
    const int t = it * 16 + llo;
    const int byte0 = (t * 256 + (w * 32 + lhi * 4) * 2) ^ SWZ(t);
    const int byte1 = (t * 256 + (w * 32 + 16 + lhi * 4) * 2) ^ SWZ(t);
    u32x2 w0, w1;
    w0.x = cvtpk(o0[0] * inv, o0[1] * inv);
    w0.y = cvtpk(o0[2] * inv, o0[3] * inv);
    w1.x = cvtpk(o1[0] * inv, o1[1] * inv);
    w1.y = cvtpk(o1[2] * inv, o1[3] * inv);
    *(u32x2*)(lds + byte0) = w0;
    *(u32x2*)(lds + byte1) = w1;
  }

  // ---- Phase 6: proj with C[token][och] (A = AO token rows, B = wp och rows)
  // so each lane's 4 acc regs = 4 CONSECUTIVE PIXELS of one channel ->
  // coalesced f32x4 stores (R3's C[och][token] gave 4B scattered stores,
  // WRITE_SIZE 400 MB vs 256 ideal).
  bf16x8 wpf[2][4];
  float pb2[2];
#pragma unroll
  for (int ot = 0; ot < 2; ++ot) {
#pragma unroll
    for (int ks = 0; ks < 4; ++ks)
      wpf[ot][ks] = *(const bf16x8*)(wp + (w * 32 + ot * 16 + llo) * 128 + ks * 32 + lhi * 8);
    pb2[ot] = proj_b[w * 32 + ot * 16 + llo];
  }
  __syncthreads();  // AO complete

  float* ob = out + (size_t)b * 128 * 65536;
#pragma unroll
  for (int it = 0; it < 4; ++it) {
    const int t = it * 16 + llo;
    bf16x8 af[4];
#pragma unroll
    for (int ks = 0; ks < 4; ++ks)
      af[ks] = *(const bf16x8*)(lds + ((t * 256 + ks * 64 + lhi * 16) ^ SWZ(t)));
#pragma unroll
    for (int ot = 0; ot < 2; ++ot) {
      f32x4 acc = {0.f, 0.f, 0.f, 0.f};
#pragma unroll
      for (int ks = 0; ks < 4; ++ks) acc = MFMA(af[ks], wpf[ot][ks], acc);
      // lane holds tokens tq..tq+3 (4 consecutive pixels) of channel ch
      const int ch = w * 32 + ot * 16 + llo;
      const int tq = it * 16 + lhi * 4;
      f32x4 v4 = {acc[0] + pb2[ot], acc[1] + pb2[ot],
                  acc[2] + pb2[ot], acc[3] + pb2[ot]};
      *(f32x4*)(ob + (size_t)ch * 65536 + (y0 + (tq >> 3)) * 256 + x0 + (tq & 7)) = v4;
    }
  }
}

extern "C" void kernel_launch(void* const* d_in, const int* in_sizes, int n_in,
                              void* d_out, int out_size, void* d_ws, size_t ws_size,
                              hipStream_t stream) {
  const float* x = (const float*)d_in[0];
  const float* qkv_w = (const float*)d_in[1];
  const float* qkv_b = (const float*)d_in[2];
  const float* proj_w = (const float*)d_in[3];
  const float* proj_b = (const float*)d_in[4];
  const float* tbl = (const float*)d_in[5];
  const int* ridx = (const int*)d_in[6];
  float* out = (float*)d_out;

  char* ws = (char*)d_ws;
  short* wq = (short*)ws;                    //      0 .. 98304: qkv_w bf16 (Q pre-scaled)
  short* wp = (short*)(ws + 98304);          //  98304 ..131072: proj_w bf16
  float* qb = (float*)(ws + 131072);         // 131072 ..132608: scaled qkv_b f32
  float* bfr = (float*)(ws + 132608);        // 132608 ..198144: bias, transposed frag order

  prep_kernel<<<64, 256, 0, stream>>>(qkv_w, qkv_b, proj_w, tbl, ridx, wq, wp, qb, bfr);
  winattn_kernel<<<8192, 256, 0, stream>>>(x, proj_b, wq, wp, qb, bfr, out);
}

// Round 6
// 339.331 us; speedup vs baseline: 3.6322x; 1.4945x over previous
//
#include <hip/hip_runtime.h>

typedef __attribute__((ext_vector_type(8))) short bf16x8;
typedef __attribute__((ext_vector_type(4))) float f32x4;
typedef __attribute__((ext_vector_type(2))) unsigned u32x2;

#define MFMA(a, b, c) __builtin_amdgcn_mfma_f32_16x16x32_bf16((a), (b), (c), 0, 0, 0)
#define Q_SCALE 0.17677669529663687f /* 32^-0.5 */
// XOR swizzle for 256B-row token-major tiles (XS / AO).
// Row stride 256B == 0 mod 128B -> all rows alias the same banks; fragment
// READS vary t bits 0..3 within a 16-lane group, phase-0 WRITES vary t bits
// 2..5.  t ^ (t>>3) feeds both ranges into the 16B-column selector:
// reads become 2-way (was 4-way), writes stay 4-way.
// Swizzle bits live at byte bits 4-6 -> compute full address BEFORE XOR,
// and recompute per element when t changes (t low bits now participate).
#define SWZ(t) ((((t) ^ ((t) >> 3)) & 7) << 4)

__device__ __forceinline__ short f2bf(float f) {
  union { float f; unsigned u; } c; c.f = f;
  unsigned u = c.u;
  return (short)((u + 0x7FFFu + ((u >> 16) & 1u)) >> 16);  // RNE
}

__device__ __forceinline__ unsigned cvtpk(float lo, float hi) {
  unsigned r;
  asm("v_cvt_pk_bf16_f32 %0, %1, %2" : "=v"(r) : "v"(lo), "v"(hi));
  return r;
}

// v_permlane32_swap_b32: a' = [a.lanes0-31 | b.lanes0-31], b' = [a.hi | b.hi]
__device__ __forceinline__ void pl32swap(unsigned& a, unsigned& b) {
  asm("v_permlane32_swap_b32 %0, %1" : "+v"(a), "+v"(b));
}
// lane l -> lane l^16 within each 32-lane half (bank-conflict-free)
__device__ __forceinline__ unsigned swz16(unsigned x) {
  return (unsigned)__builtin_amdgcn_ds_swizzle((int)x, 0x401F);
}

// C-frag -> A/B-frag lane exchange (intra-wave), conflict-free.
// dest lane (llo,lhi) gets 8 consecutive k at k0 = lhi*8 from tile (lhi>>1);
// odd = lhi&1. With r0=[pa_lo|pb_lo], r1=[pa_hi|pb_hi]:
//   u[0]=odd?swz16(r1):r0,  u[2]=odd?r1:swz16(r0)  (same for pair 1).
__device__ __forceinline__ bf16x8 xch2(unsigned pa0, unsigned pa1,
                                       unsigned pb0, unsigned pb1, int odd) {
  unsigned a0 = pa0, b0 = pb0, a1 = pa1, b1 = pb1;
  pl32swap(a0, b0);
  pl32swap(a1, b1);
  unsigned s0 = swz16(b0), s1 = swz16(b1);
  unsigned t0 = swz16(a0), t1 = swz16(a1);
  union { unsigned u[4]; bf16x8 v; } r;
  r.u[0] = odd ? s0 : a0;
  r.u[1] = odd ? s1 : a1;
  r.u[2] = odd ? b0 : t0;
  r.u[3] = odd ? b1 : t1;
  return r.v;
}

// ---------------------------------------------------------------------------
// prep: bf16 weights (Q rows pre-scaled), scaled qkv bias, bias table gathered
// in TRANSPOSED C-frag order: rows = key j, cols = query i.
// ---------------------------------------------------------------------------
__global__ void prep_kernel(const float* __restrict__ qkv_w,
                            const float* __restrict__ qkv_b,
                            const float* __restrict__ proj_w,
                            const float* __restrict__ tbl,
                            const int* __restrict__ ridx,
                            short* __restrict__ wq, short* __restrict__ wp,
                            float* __restrict__ qb, float* __restrict__ bfr) {
  const int stride = gridDim.x * blockDim.x;
  const int tid = blockIdx.x * blockDim.x + threadIdx.x;
  for (int i = tid; i < 384 * 128; i += stride)
    wq[i] = f2bf(qkv_w[i] * (i < 128 * 128 ? Q_SCALE : 1.f));
  for (int i = tid; i < 128 * 128; i += stride) wp[i] = f2bf(proj_w[i]);
  for (int i = tid; i < 384; i += stride)
    qb[i] = qkv_b[i] * (i < 128 ? Q_SCALE : 1.f);
  for (int i = tid; i < 4 * 64 * 64; i += stride) {
    int reg = i & 3, it = (i >> 2) & 3, jt = (i >> 4) & 3;
    int l = (i >> 6) & 63, h = i >> 12;
    int qi = it * 16 + (l & 15);            // query (column)
    int kj = jt * 16 + (l >> 4) * 4 + reg;  // key (row)
    bfr[i] = tbl[ridx[qi * 64 + kj] * 4 + h];
  }
}

// ---------------------------------------------------------------------------
// fused window attention, register-resident QKV/P (wave = head).
// LDS: single 16 KB token-major [64][128] bf16 region, XOR-swizzled:
//   phase 0/1: XS (x tile);  phase 4/6: AO (attn output, pre-proj).
// launch_bounds(256,3): empirically N blocks/CU resident, VGPR budget 512/N;
// N=4/6 caused scratch spills (FETCH inflation) -> stay at 3.
// ---------------------------------------------------------------------------
__global__ __launch_bounds__(256, 3) void winattn_kernel(
    const float* __restrict__ x, const float* __restrict__ proj_b,
    const short* __restrict__ wq, const short* __restrict__ wp,
    const float* __restrict__ qb, const float* __restrict__ bfr,
    float* __restrict__ out) {
  __shared__ __align__(16) char lds[16384];

  const int tid = threadIdx.x;
  const int w = tid >> 6;  // wave id == head
  const int l = tid & 63;
  const int llo = l & 15, lhi = l >> 4;
  const int odd = lhi & 1;

  // XCD-bijective swizzle (8192 % 8 == 0)
  const int bid = blockIdx.x;
  const int wid = (bid & 7) * 1024 + (bid >> 3);
  const int b = wid >> 10;
  const int wy = (wid >> 5) & 31, wx = wid & 31;
  const int y0 = wy * 8, x0 = wx * 8;

  // ---- Phase 0: issue ALL x loads first (8 independent HBM loads in
  // flight), then prefetch grp-0 weight fragments (L2), then scatter.
  const float* xb = x + (size_t)b * 128 * 65536;
  f32x4 xv[8];
#pragma unroll
  for (int k = 0; k < 8; ++k) {
    int u = tid + k * 256;
    int c = u >> 4, i = (u >> 1) & 7, j4 = u & 1;
    xv[k] = *(const f32x4*)(xb + (size_t)c * 65536 + (y0 + i) * 256 + x0 + j4 * 4);
  }
  bf16x8 wf0[3][4];  // grp-0 weight fragments, prefetched behind x loads
#pragma unroll
  for (int gi = 0; gi < 3; ++gi) {
    const int rowbase = (gi >> 1) * 128 + w * 32 + (gi & 1) * 16;
#pragma unroll
    for (int ks = 0; ks < 4; ++ks)
      wf0[gi][ks] = *(const bf16x8*)(wq + (rowbase + llo) * 128 + ks * 32 + lhi * 8);
  }
#pragma unroll
  for (int k = 0; k < 8; ++k) {
    int u = tid + k * 256;
    int c = u >> 4, i = (u >> 1) & 7, j4 = u & 1;
    int t0 = i * 8 + j4 * 4;
#pragma unroll
    for (int n = 0; n < 4; ++n)  // SWZ depends on t low bits: per-elem addr
      *(short*)(lds + (((t0 + n) * 256 + c * 2) ^ SWZ(t0 + n))) = f2bf(xv[k][n]);
  }
  __syncthreads();

  // ---- Phase 1: QKV GEMM, outputs packed bf16 in registers.
  // g 0,1 = Q tiles (C[o][t]); 2,3 = K tiles (C[o][t]); 4,5 = V tiles (C[t][d])
  unsigned pkq[2][4][2], pkk[2][4][2], pkv[2][4][2];
#pragma unroll
  for (int grp = 0; grp < 2; ++grp) {
    bf16x8 wf[3][4];
    f32x4 qb4[3];
    float bv[3];
#pragma unroll
    for (int gi = 0; gi < 3; ++gi) {
      const int g = grp * 3 + gi;
      const int rowbase = (g >> 1) * 128 + w * 32 + (g & 1) * 16;
      if (grp == 0) {
#pragma unroll
        for (int ks = 0; ks < 4; ++ks) wf[gi][ks] = wf0[gi][ks];
      } else {
#pragma unroll
        for (int ks = 0; ks < 4; ++ks)
          wf[gi][ks] = *(const bf16x8*)(wq + (rowbase + llo) * 128 + ks * 32 + lhi * 8);
      }
      if (g < 4)
        qb4[gi] = *(const f32x4*)(qb + rowbase + lhi * 4);
      else
        bv[gi] = qb[rowbase + llo];
    }
#pragma unroll
    for (int tt = 0; tt < 4; ++tt) {
      bf16x8 xf[4];
      const int t = tt * 16 + llo;
#pragma unroll
      for (int ks = 0; ks < 4; ++ks)
        xf[ks] = *(const bf16x8*)(lds + ((t * 256 + ks * 64 + lhi * 16) ^ SWZ(t)));
#pragma unroll
      for (int gi = 0; gi < 3; ++gi) {
        const int g = grp * 3 + gi;
        f32x4 acc = {0.f, 0.f, 0.f, 0.f};
        if (g < 4) {
#pragma unroll
          for (int ks = 0; ks < 4; ++ks) acc = MFMA(wf[gi][ks], xf[ks], acc);
          unsigned d0 = cvtpk(acc[0] + qb4[gi][0], acc[1] + qb4[gi][1]);
          unsigned d1 = cvtpk(acc[2] + qb4[gi][2], acc[3] + qb4[gi][3]);
          if (g < 2) { pkq[g][tt][0] = d0; pkq[g][tt][1] = d1; }
          else       { pkk[g - 2][tt][0] = d0; pkk[g - 2][tt][1] = d1; }
        } else {
#pragma unroll
          for (int ks = 0; ks < 4; ++ks) acc = MFMA(xf[ks], wf[gi][ks], acc);
          pkv[g - 4][tt][0] = cvtpk(acc[0] + bv[gi], acc[1] + bv[gi]);
          pkv[g - 4][tt][1] = cvtpk(acc[2] + bv[gi], acc[3] + bv[gi]);
        }
      }
    }
  }
  __syncthreads();  // XS dead -> AO region writable later

  // ---- Build K A-frags and V A-frags; prefetch it=0 bias behind them
  const f32x4* bias4 = (const f32x4*)bfr + ((w * 64 + l) << 4);
  bf16x8 kf[4], va[2][2];
  f32x4 biasreg[4];
#pragma unroll
  for (int jt = 0; jt < 4; ++jt) biasreg[jt] = bias4[jt * 4];  // it = 0
#pragma unroll
  for (int jt = 0; jt < 4; ++jt)
    kf[jt] = xch2(pkk[0][jt][0], pkk[0][jt][1], pkk[1][jt][0], pkk[1][jt][1], odd);
#pragma unroll
  for (int vt = 0; vt < 2; ++vt)
#pragma unroll
    for (int ks = 0; ks < 2; ++ks)
      va[vt][ks] = xch2(pkv[vt][2 * ks][0], pkv[vt][2 * ks][1],
                        pkv[vt][2 * ks + 1][0], pkv[vt][2 * ks + 1][1], odd);

  // ---- Phases 2-4 fused, streamed per query tile `it`
#pragma unroll
  for (int it = 0; it < 4; ++it) {
    bf16x8 qf = xch2(pkq[0][it][0], pkq[0][it][1], pkq[1][it][0], pkq[1][it][1], odd);
    f32x4 dots[4];
#pragma unroll
    for (int jt = 0; jt < 4; ++jt)
      dots[jt] = MFMA(kf[jt], qf, biasreg[jt]);  // bias as accumulator init
    // prefetch next it's bias while softmax runs (hides L2 latency)
    f32x4 biasnext[4];
    if (it < 3) {
#pragma unroll
      for (int jt = 0; jt < 4; ++jt) biasnext[jt] = bias4[jt * 4 + it + 1];
    }
    // softmax over key axis: 16 lane-local values + 2 cross-lhi shfls
    float m = dots[0][0];
#pragma unroll
    for (int jt = 0; jt < 4; ++jt)
#pragma unroll
      for (int r = 0; r < 4; ++r) m = fmaxf(m, dots[jt][r]);
    m = fmaxf(m, __shfl_xor(m, 16));
    m = fmaxf(m, __shfl_xor(m, 32));
    float p[4][4];
    float s = 0.f;
#pragma unroll
    for (int jt = 0; jt < 4; ++jt)
#pragma unroll
      for (int r = 0; r < 4; ++r) {
        p[jt][r] = __expf(dots[jt][r] - m);
        s += p[jt][r];
      }
    s += __shfl_xor(s, 16);
    s += __shfl_xor(s, 32);
    const float inv = 1.f / s;
    unsigned pk[4][2];
#pragma unroll
    for (int jt = 0; jt < 4; ++jt) {
      pk[jt][0] = cvtpk(p[jt][0], p[jt][1]);
      pk[jt][1] = cvtpk(p[jt][2], p[jt][3]);
    }
    bf16x8 pb0 = xch2(pk[0][0], pk[0][1], pk[1][0], pk[1][1], odd);
    bf16x8 pb1 = xch2(pk[2][0], pk[2][1], pk[3][0], pk[3][1], odd);
    // PV: C[d][t] (rows = d, cols = query token)
    f32x4 o0 = {0.f, 0.f, 0.f, 0.f}, o1 = {0.f, 0.f, 0.f, 0.f};
    o0 = MFMA(va[0][0], pb0, o0);
    o0 = MFMA(va[0][1], pb1, o0);
    o1 = MFMA(va[1][0], pb0, o1);
    o1 = MFMA(va[1][1], pb1, o1);
    // normalize + write AO[t][c] (c = head*32 + d), packed b64, swizzled.
    // Full byte address computed BEFORE the XOR.
    const int t = it * 16 + llo;
    const int byte0 = (t * 256 + (w * 32 + lhi * 4) * 2) ^ SWZ(t);
    const int byte1 = (t * 256 + (w * 32 + 16 + lhi * 4) * 2) ^ SWZ(t);
    u32x2 w0, w1;
    w0.x = cvtpk(o0[0] * inv, o0[1] * inv);
    w0.y = cvtpk(o0[2] * inv, o0[3] * inv);
    w1.x = cvtpk(o1[0] * inv, o1[1] * inv);
    w1.y = cvtpk(o1[2] * inv, o1[3] * inv);
    *(u32x2*)(lds + byte0) = w0;
    *(u32x2*)(lds + byte1) = w1;
#pragma unroll
    for (int jt = 0; jt < 4; ++jt) biasreg[jt] = biasnext[jt];
  }

  // ---- Phase 6: proj with C[token][och] (A = AO token rows, B = wp och rows)
  // -> each lane's 4 acc regs = 4 consecutive pixels of one channel ->
  // coalesced f32x4 stores.
  bf16x8 wpf[2][4];
  float pb2[2];
#pragma unroll
  for (int ot = 0; ot < 2; ++ot) {
#pragma unroll
    for (int ks = 0; ks < 4; ++ks)
      wpf[ot][ks] = *(const bf16x8*)(wp + (w * 32 + ot * 16 + llo) * 128 + ks * 32 + lhi * 8);
    pb2[ot] = proj_b[w * 32 + ot * 16 + llo];
  }
  __syncthreads();  // AO complete

  float* ob = out + (size_t)b * 128 * 65536;
#pragma unroll
  for (int it = 0; it < 4; ++it) {
    const int t = it * 16 + llo;
    bf16x8 af[4];
#pragma unroll
    for (int ks = 0; ks < 4; ++ks)
      af[ks] = *(const bf16x8*)(lds + ((t * 256 + ks * 64 + lhi * 16) ^ SWZ(t)));
#pragma unroll
    for (int ot = 0; ot < 2; ++ot) {
      f32x4 acc = {0.f, 0.f, 0.f, 0.f};
#pragma unroll
      for (int ks = 0; ks < 4; ++ks) acc = MFMA(af[ks], wpf[ot][ks], acc);
      // lane holds tokens tq..tq+3 (4 consecutive pixels) of channel ch
      const int ch = w * 32 + ot * 16 + llo;
      const int tq = it * 16 + lhi * 4;
      f32x4 v4 = {acc[0] + pb2[ot], acc[1] + pb2[ot],
                  acc[2] + pb2[ot], acc[3] + pb2[ot]};
      *(f32x4*)(ob + (size_t)ch * 65536 + (y0 + (tq >> 3)) * 256 + x0 + (tq & 7)) = v4;
    }
  }
}

extern "C" void kernel_launch(void* const* d_in, const int* in_sizes, int n_in,
                              void* d_out, int out_size, void* d_ws, size_t ws_size,
                              hipStream_t stream) {
  const float* x = (const float*)d_in[0];
  const float* qkv_w = (const float*)d_in[1];
  const float* qkv_b = (const float*)d_in[2];
  const float* proj_w = (const float*)d_in[3];
  const float* proj_b = (const float*)d_in[4];
  const float* tbl = (const float*)d_in[5];
  const int* ridx = (const int*)d_in[6];
  float* out = (float*)d_out;

  char* ws = (char*)d_ws;
  short* wq = (short*)ws;                    //      0 .. 98304: qkv_w bf16 (Q pre-scaled)
  short* wp = (short*)(ws + 98304);          //  98304 ..131072: proj_w bf16
  float* qb = (float*)(ws + 131072);         // 131072 ..132608: scaled qkv_b f32
  float* bfr = (float*)(ws + 132608);        // 132608 ..198144: bias, transposed frag order

  prep_kernel<<<64, 256, 0, stream>>>(qkv_w, qkv_b, proj_w, tbl, ridx, wq, wp, qb, bfr);
  winattn_kernel<<<8192, 256, 0, stream>>>(x, proj_b, wq, wp, qb, bfr, out);
}

// Round 7
// 301.244 us; speedup vs baseline: 4.0914x; 1.1264x over previous
//
#include <hip/hip_runtime.h>

typedef __attribute__((ext_vector_type(8))) short bf16x8;
typedef __attribute__((ext_vector_type(4))) float f32x4;
typedef __attribute__((ext_vector_type(2))) unsigned u32x2;

#define MFMA(a, b, c) __builtin_amdgcn_mfma_f32_16x16x32_bf16((a), (b), (c), 0, 0, 0)
#define Q_SCALE 0.17677669529663687f /* 32^-0.5 */
// XOR swizzle for 256B-row token-major tiles (XS / AO).
// Row stride 256B == 0 mod 128B -> all rows alias the same banks; fragment
// READS vary t bits 0..3 within a 16-lane group, phase-0 WRITES vary t bits
// 2..5.  t ^ (t>>3) feeds both ranges into the 16B-column selector.
// Swizzle bits live at byte bits 4-6 -> compute full address BEFORE XOR.
#define SWZ(t) ((((t) ^ ((t) >> 3)) & 7) << 4)

__device__ __forceinline__ short f2bf(float f) {
  union { float f; unsigned u; } c; c.f = f;
  unsigned u = c.u;
  return (short)((u + 0x7FFFu + ((u >> 16) & 1u)) >> 16);  // RNE
}

__device__ __forceinline__ unsigned cvtpk(float lo, float hi) {
  unsigned r;
  asm("v_cvt_pk_bf16_f32 %0, %1, %2" : "=v"(r) : "v"(lo), "v"(hi));
  return r;
}

// v_permlane32_swap_b32: a' = [a.lanes0-31 | b.lanes0-31], b' = [a.hi | b.hi]
__device__ __forceinline__ void pl32swap(unsigned& a, unsigned& b) {
  asm("v_permlane32_swap_b32 %0, %1" : "+v"(a), "+v"(b));
}
// lane l -> lane l^16 within each 32-lane half (bank-conflict-free)
__device__ __forceinline__ unsigned swz16(unsigned x) {
  return (unsigned)__builtin_amdgcn_ds_swizzle((int)x, 0x401F);
}

// C-frag -> A/B-frag lane exchange (intra-wave), conflict-free.
// dest lane (llo,lhi) gets 8 consecutive k at k0 = lhi*8 from tile (lhi>>1);
// odd = lhi&1. With r0=[pa_lo|pb_lo], r1=[pa_hi|pb_hi]:
//   u[0]=odd?swz16(r1):r0,  u[2]=odd?r1:swz16(r0)  (same for pair 1).
__device__ __forceinline__ bf16x8 xch2(unsigned pa0, unsigned pa1,
                                       unsigned pb0, unsigned pb1, int odd) {
  unsigned a0 = pa0, b0 = pb0, a1 = pa1, b1 = pb1;
  pl32swap(a0, b0);
  pl32swap(a1, b1);
  unsigned s0 = swz16(b0), s1 = swz16(b1);
  unsigned t0 = swz16(a0), t1 = swz16(a1);
  union { unsigned u[4]; bf16x8 v; } r;
  r.u[0] = odd ? s0 : a0;
  r.u[1] = odd ? s1 : a1;
  r.u[2] = odd ? b0 : t0;
  r.u[3] = odd ? b1 : t1;
  return r.v;
}

// ---------------------------------------------------------------------------
// prep: bf16 weights (Q rows pre-scaled), scaled qkv bias, bias table gathered
// in TRANSPOSED C-frag order: rows = key j, cols = query i.
// ---------------------------------------------------------------------------
__global__ void prep_kernel(const float* __restrict__ qkv_w,
                            const float* __restrict__ qkv_b,
                            const float* __restrict__ proj_w,
                            const float* __restrict__ tbl,
                            const int* __restrict__ ridx,
                            short* __restrict__ wq, short* __restrict__ wp,
                            float* __restrict__ qb, float* __restrict__ bfr) {
  const int stride = gridDim.x * blockDim.x;
  const int tid = blockIdx.x * blockDim.x + threadIdx.x;
  for (int i = tid; i < 384 * 128; i += stride)
    wq[i] = f2bf(qkv_w[i] * (i < 128 * 128 ? Q_SCALE : 1.f));
  for (int i = tid; i < 128 * 128; i += stride) wp[i] = f2bf(proj_w[i]);
  for (int i = tid; i < 384; i += stride)
    qb[i] = qkv_b[i] * (i < 128 ? Q_SCALE : 1.f);
  for (int i = tid; i < 4 * 64 * 64; i += stride) {
    int reg = i & 3, it = (i >> 2) & 3, jt = (i >> 4) & 3;
    int l = (i >> 6) & 63, h = i >> 12;
    int qi = it * 16 + (l & 15);            // query (column)
    int kj = jt * 16 + (l >> 4) * 4 + reg;  // key (row)
    bfr[i] = tbl[ridx[qi * 64 + kj] * 4 + h];
  }
}

// ---------------------------------------------------------------------------
// fused window attention, register-resident QKV/P (wave = head).
// LDS: single 16 KB token-major [64][128] bf16 region, XOR-swizzled:
//   phase 0/1: XS (x tile);  phase 4/6: AO (attn output, pre-proj).
// NO waves-per-EU hint: measured law on this toolchain is occupancy ==
// 2nd-arg blocks/CU AND VGPR budget ~= 256/N (N=3 fit 84; N=4 squeezed
// to 64 + refetch; N=6 spilled to 40).  With no hint the compiler gets
// budget 256 (no spill) and HW resource math sets occupancy (~4-5
// blocks/CU at ~84-96 VGPR, LDS admits 10).
// ---------------------------------------------------------------------------
__global__ __launch_bounds__(256) void winattn_kernel(
    const float* __restrict__ x, const float* __restrict__ proj_b,
    const short* __restrict__ wq, const short* __restrict__ wp,
    const float* __restrict__ qb, const float* __restrict__ bfr,
    float* __restrict__ out) {
  __shared__ __align__(16) char lds[16384];

  const int tid = threadIdx.x;
  const int w = tid >> 6;  // wave id == head
  const int l = tid & 63;
  const int llo = l & 15, lhi = l >> 4;
  const int odd = lhi & 1;

  // XCD-bijective swizzle (8192 % 8 == 0)
  const int bid = blockIdx.x;
  const int wid = (bid & 7) * 1024 + (bid >> 3);
  const int b = wid >> 10;
  const int wy = (wid >> 5) & 31, wx = wid & 31;
  const int y0 = wy * 8, x0 = wx * 8;

  // ---- Phase 0: issue ALL x loads first (8 independent HBM loads in
  // flight), then scatter to LDS.
  const float* xb = x + (size_t)b * 128 * 65536;
  f32x4 xv[8];
#pragma unroll
  for (int k = 0; k < 8; ++k) {
    int u = tid + k * 256;
    int c = u >> 4, i = (u >> 1) & 7, j4 = u & 1;
    xv[k] = *(const f32x4*)(xb + (size_t)c * 65536 + (y0 + i) * 256 + x0 + j4 * 4);
  }
#pragma unroll
  for (int k = 0; k < 8; ++k) {
    int u = tid + k * 256;
    int c = u >> 4, i = (u >> 1) & 7, j4 = u & 1;
    int t0 = i * 8 + j4 * 4;
#pragma unroll
    for (int n = 0; n < 4; ++n)  // SWZ depends on t low bits: per-elem addr
      *(short*)(lds + (((t0 + n) * 256 + c * 2) ^ SWZ(t0 + n))) = f2bf(xv[k][n]);
  }
  __syncthreads();

  // ---- Phase 1: QKV GEMM, outputs packed bf16 in registers.
  // g 0,1 = Q tiles (C[o][t]); 2,3 = K tiles (C[o][t]); 4,5 = V tiles (C[t][d])
  unsigned pkq[2][4][2], pkk[2][4][2], pkv[2][4][2];
#pragma unroll
  for (int grp = 0; grp < 2; ++grp) {
    bf16x8 wf[3][4];
    f32x4 qb4[3];
    float bv[3];
#pragma unroll
    for (int gi = 0; gi < 3; ++gi) {
      const int g = grp * 3 + gi;
      const int rowbase = (g >> 1) * 128 + w * 32 + (g & 1) * 16;
#pragma unroll
      for (int ks = 0; ks < 4; ++ks)
        wf[gi][ks] = *(const bf16x8*)(wq + (rowbase + llo) * 128 + ks * 32 + lhi * 8);
      if (g < 4)
        qb4[gi] = *(const f32x4*)(qb + rowbase + lhi * 4);
      else
        bv[gi] = qb[rowbase + llo];
    }
#pragma unroll
    for (int tt = 0; tt < 4; ++tt) {
      bf16x8 xf[4];
      const int t = tt * 16 + llo;
#pragma unroll
      for (int ks = 0; ks < 4; ++ks)
        xf[ks] = *(const bf16x8*)(lds + ((t * 256 + ks * 64 + lhi * 16) ^ SWZ(t)));
#pragma unroll
      for (int gi = 0; gi < 3; ++gi) {
        const int g = grp * 3 + gi;
        f32x4 acc = {0.f, 0.f, 0.f, 0.f};
        if (g < 4) {
#pragma unroll
          for (int ks = 0; ks < 4; ++ks) acc = MFMA(wf[gi][ks], xf[ks], acc);
          unsigned d0 = cvtpk(acc[0] + qb4[gi][0], acc[1] + qb4[gi][1]);
          unsigned d1 = cvtpk(acc[2] + qb4[gi][2], acc[3] + qb4[gi][3]);
          if (g < 2) { pkq[g][tt][0] = d0; pkq[g][tt][1] = d1; }
          else       { pkk[g - 2][tt][0] = d0; pkk[g - 2][tt][1] = d1; }
        } else {
#pragma unroll
          for (int ks = 0; ks < 4; ++ks) acc = MFMA(xf[ks], wf[gi][ks], acc);
          pkv[g - 4][tt][0] = cvtpk(acc[0] + bv[gi], acc[1] + bv[gi]);
          pkv[g - 4][tt][1] = cvtpk(acc[2] + bv[gi], acc[3] + bv[gi]);
        }
      }
    }
  }
  __syncthreads();  // XS dead -> AO region writable later

  // ---- Build K A-frags and V A-frags; prefetch it=0 bias behind them
  const f32x4* bias4 = (const f32x4*)bfr + ((w * 64 + l) << 4);
  bf16x8 kf[4], va[2][2];
  f32x4 biasreg[4];
#pragma unroll
  for (int jt = 0; jt < 4; ++jt) biasreg[jt] = bias4[jt * 4];  // it = 0
#pragma unroll
  for (int jt = 0; jt < 4; ++jt)
    kf[jt] = xch2(pkk[0][jt][0], pkk[0][jt][1], pkk[1][jt][0], pkk[1][jt][1], odd);
#pragma unroll
  for (int vt = 0; vt < 2; ++vt)
#pragma unroll
    for (int ks = 0; ks < 2; ++ks)
      va[vt][ks] = xch2(pkv[vt][2 * ks][0], pkv[vt][2 * ks][1],
                        pkv[vt][2 * ks + 1][0], pkv[vt][2 * ks + 1][1], odd);

  // ---- Phases 2-4 fused, streamed per query tile `it`
#pragma unroll
  for (int it = 0; it < 4; ++it) {
    bf16x8 qf = xch2(pkq[0][it][0], pkq[0][it][1], pkq[1][it][0], pkq[1][it][1], odd);
    f32x4 dots[4];
#pragma unroll
    for (int jt = 0; jt < 4; ++jt)
      dots[jt] = MFMA(kf[jt], qf, biasreg[jt]);  // bias as accumulator init
    // prefetch next it's bias while softmax runs (hides L2 latency)
    f32x4 biasnext[4];
    if (it < 3) {
#pragma unroll
      for (int jt = 0; jt < 4; ++jt) biasnext[jt] = bias4[jt * 4 + it + 1];
    }
    // softmax over key axis: 16 lane-local values + 2 cross-lhi shfls
    float m = dots[0][0];
#pragma unroll
    for (int jt = 0; jt < 4; ++jt)
#pragma unroll
      for (int r = 0; r < 4; ++r) m = fmaxf(m, dots[jt][r]);
    m = fmaxf(m, __shfl_xor(m, 16));
    m = fmaxf(m, __shfl_xor(m, 32));
    float p[4][4];
    float s = 0.f;
#pragma unroll
    for (int jt = 0; jt < 4; ++jt)
#pragma unroll
      for (int r = 0; r < 4; ++r) {
        p[jt][r] = __expf(dots[jt][r] - m);
        s += p[jt][r];
      }
    s += __shfl_xor(s, 16);
    s += __shfl_xor(s, 32);
    const float inv = 1.f / s;
    unsigned pk[4][2];
#pragma unroll
    for (int jt = 0; jt < 4; ++jt) {
      pk[jt][0] = cvtpk(p[jt][0], p[jt][1]);
      pk[jt][1] = cvtpk(p[jt][2], p[jt][3]);
    }
    bf16x8 pb0 = xch2(pk[0][0], pk[0][1], pk[1][0], pk[1][1], odd);
    bf16x8 pb1 = xch2(pk[2][0], pk[2][1], pk[3][0], pk[3][1], odd);
    // PV: C[d][t] (rows = d, cols = query token)
    f32x4 o0 = {0.f, 0.f, 0.f, 0.f}, o1 = {0.f, 0.f, 0.f, 0.f};
    o0 = MFMA(va[0][0], pb0, o0);
    o0 = MFMA(va[0][1], pb1, o0);
    o1 = MFMA(va[1][0], pb0, o1);
    o1 = MFMA(va[1][1], pb1, o1);
    // normalize + write AO[t][c] (c = head*32 + d), packed b64, swizzled.
    // Full byte address computed BEFORE the XOR.
    const int t = it * 16 + llo;
    const int byte0 = (t * 256 + (w * 32 + lhi * 4) * 2) ^ SWZ(t);
    const int byte1 = (t * 256 + (w * 32 + 16 + lhi * 4) * 2) ^ SWZ(t);
    u32x2 w0, w1;
    w0.x = cvtpk(o0[0] * inv, o0[1] * inv);
    w0.y = cvtpk(o0[2] * inv, o0[3] * inv);
    w1.x = cvtpk(o1[0] * inv, o1[1] * inv);
    w1.y = cvtpk(o1[2] * inv, o1[3] * inv);
    *(u32x2*)(lds + byte0) = w0;
    *(u32x2*)(lds + byte1) = w1;
#pragma unroll
    for (int jt = 0; jt < 4; ++jt) biasreg[jt] = biasnext[jt];
  }

  // ---- Phase 6: proj with C[token][och] (A = AO token rows, B = wp och rows)
  // -> each lane's 4 acc regs = 4 consecutive pixels of one channel ->
  // coalesced f32x4 stores.
  bf16x8 wpf[2][4];
  float pb2[2];
#pragma unroll
  for (int ot = 0; ot < 2; ++ot) {
#pragma unroll
    for (int ks = 0; ks < 4; ++ks)
      wpf[ot][ks] = *(const bf16x8*)(wp + (w * 32 + ot * 16 + llo) * 128 + ks * 32 + lhi * 8);
    pb2[ot] = proj_b[w * 32 + ot * 16 + llo];
  }
  __syncthreads();  // AO complete

  float* ob = out + (size_t)b * 128 * 65536;
#pragma unroll
  for (int it = 0; it < 4; ++it) {
    const int t = it * 16 + llo;
    bf16x8 af[4];
#pragma unroll
    for (int ks = 0; ks < 4; ++ks)
      af[ks] = *(const bf16x8*)(lds + ((t * 256 + ks * 64 + lhi * 16) ^ SWZ(t)));
#pragma unroll
    for (int ot = 0; ot < 2; ++ot) {
      f32x4 acc = {0.f, 0.f, 0.f, 0.f};
#pragma unroll
      for (int ks = 0; ks < 4; ++ks) acc = MFMA(af[ks], wpf[ot][ks], acc);
      // lane holds tokens tq..tq+3 (4 consecutive pixels) of channel ch
      const int ch = w * 32 + ot * 16 + llo;
      const int tq = it * 16 + lhi * 4;
      f32x4 v4 = {acc[0] + pb2[ot], acc[1] + pb2[ot],
                  acc[2] + pb2[ot], acc[3] + pb2[ot]};
      *(f32x4*)(ob + (size_t)ch * 65536 + (y0 + (tq >> 3)) * 256 + x0 + (tq & 7)) = v4;
    }
  }
}

extern "C" void kernel_launch(void* const* d_in, const int* in_sizes, int n_in,
                              void* d_out, int out_size, void* d_ws, size_t ws_size,
                              hipStream_t stream) {
  const float* x = (const float*)d_in[0];
  const float* qkv_w = (const float*)d_in[1];
  const float* qkv_b = (const float*)d_in[2];
  const float* proj_w = (const float*)d_in[3];
  const float* proj_b = (const float*)d_in[4];
  const float* tbl = (const float*)d_in[5];
  const int* ridx = (const int*)d_in[6];
  float* out = (float*)d_out;

  char* ws = (char*)d_ws;
  short* wq = (short*)ws;                    //      0 .. 98304: qkv_w bf16 (Q pre-scaled)
  short* wp = (short*)(ws + 98304);          //  98304 ..131072: proj_w bf16
  float* qb = (float*)(ws + 131072);         // 131072 ..132608: scaled qkv_b f32
  float* bfr = (float*)(ws + 132608);        // 132608 ..198144: bias, transposed frag order

  prep_kernel<<<64, 256, 0, stream>>>(qkv_w, qkv_b, proj_w, tbl, ridx, wq, wp, qb, bfr);
  winattn_kernel<<<8192, 256, 0, stream>>>(x, proj_b, wq, wp, qb, bfr, out);
}

// Round 9
// 285.102 us; speedup vs baseline: 4.3231x; 1.0566x over previous
//
#include <hip/hip_runtime.h>

typedef __attribute__((ext_vector_type(8))) short bf16x8;
typedef __attribute__((ext_vector_type(4))) float f32x4;
typedef __attribute__((ext_vector_type(2))) unsigned u32x2;

#define MFMA(a, b, c) __builtin_amdgcn_mfma_f32_16x16x32_bf16((a), (b), (c), 0, 0, 0)
#define Q_SCALE 0.17677669529663687f /* 32^-0.5 */
// XOR swizzle for 256B-row token-major tiles (XS / AO).
#define SWZ(t) ((((t) ^ ((t) >> 3)) & 7) << 4)

__device__ __forceinline__ short f2bf(float f) {
  union { float f; unsigned u; } c; c.f = f;
  unsigned u = c.u;
  return (short)((u + 0x7FFFu + ((u >> 16) & 1u)) >> 16);  // RNE
}

__device__ __forceinline__ unsigned cvtpk(float lo, float hi) {
  unsigned r;
  asm("v_cvt_pk_bf16_f32 %0, %1, %2" : "=v"(r) : "v"(lo), "v"(hi));
  return r;
}

// gfx950 permlane swap INTRINSICS (not inline asm: the asm "+v","+v" form
// miscompiles when both operands carry the same value - the copy gets
// coalesced and the emitted v_permlane*_swap_b32 v5,v5 self-swap returns
// neighbor data instead of (own,neighbor) pairs.  R8's 1.8e-3 absmax.)
// Returns {vdst', vsrc'}: 32: vdst'=[a.lo|b.lo], vsrc'=[a.hi|b.hi]
//                         16: per 32-half, rows interleave likewise.
__device__ __forceinline__ u32x2 pl32(unsigned a, unsigned b) {
  return __builtin_amdgcn_permlane32_swap(a, b, false, false);
}
__device__ __forceinline__ u32x2 pl16(unsigned a, unsigned b) {
  return __builtin_amdgcn_permlane16_swap(a, b, false, false);
}

// pure-VALU cross-lane reductions (replace LDS-based __shfl_xor)
__device__ __forceinline__ float redmax16(float x) {
  u32x2 r = pl16(__float_as_uint(x), __float_as_uint(x));
  return fmaxf(__uint_as_float(r[0]), __uint_as_float(r[1]));
}
__device__ __forceinline__ float redmax32(float x) {
  u32x2 r = pl32(__float_as_uint(x), __float_as_uint(x));
  return fmaxf(__uint_as_float(r[0]), __uint_as_float(r[1]));
}
__device__ __forceinline__ float redsum16(float x) {
  u32x2 r = pl16(__float_as_uint(x), __float_as_uint(x));
  return __uint_as_float(r[0]) + __uint_as_float(r[1]);
}
__device__ __forceinline__ float redsum32(float x) {
  u32x2 r = pl32(__float_as_uint(x), __float_as_uint(x));
  return __uint_as_float(r[0]) + __uint_as_float(r[1]);
}

// C-frag -> A/B-frag lane exchange, PURE VALU (4 swap instrs, no LDS).
// With r0=[pa.lo|pb.lo], r1=[pa.hi|pb.hi] (pl32), the pl16 swap of (r0,r1)
// yields exactly (u[0], u[2]) of the verified R4-R7 select form.
__device__ __forceinline__ bf16x8 xch2(unsigned pa0, unsigned pa1,
                                       unsigned pb0, unsigned pb1) {
  u32x2 p0 = pl32(pa0, pb0);  // p0[0]=r0 pair0, p0[1]=r1 pair0
  u32x2 p1 = pl32(pa1, pb1);  // pair1
  u32x2 q0 = pl16(p0[0], p0[1]);  // q0[0]=u[0], q0[1]=u[2]
  u32x2 q1 = pl16(p1[0], p1[1]);  // q1[0]=u[1], q1[1]=u[3]
  union { unsigned u[4]; bf16x8 v; } r;
  r.u[0] = q0[0]; r.u[1] = q1[0]; r.u[2] = q0[1]; r.u[3] = q1[1];
  return r.v;
}

// ---------------------------------------------------------------------------
// prep: bf16 weights (Q rows pre-scaled), scaled qkv bias, bias table gathered
// in TRANSPOSED C-frag order: rows = key j, cols = query i.
// ---------------------------------------------------------------------------
__global__ void prep_kernel(const float* __restrict__ qkv_w,
                            const float* __restrict__ qkv_b,
                            const float* __restrict__ proj_w,
                            const float* __restrict__ tbl,
                            const int* __restrict__ ridx,
                            short* __restrict__ wq, short* __restrict__ wp,
                            float* __restrict__ qb, float* __restrict__ bfr) {
  const int stride = gridDim.x * blockDim.x;
  const int tid = blockIdx.x * blockDim.x + threadIdx.x;
  for (int i = tid; i < 384 * 128; i += stride)
    wq[i] = f2bf(qkv_w[i] * (i < 128 * 128 ? Q_SCALE : 1.f));
  for (int i = tid; i < 128 * 128; i += stride) wp[i] = f2bf(proj_w[i]);
  for (int i = tid; i < 384; i += stride)
    qb[i] = qkv_b[i] * (i < 128 ? Q_SCALE : 1.f);
  for (int i = tid; i < 4 * 64 * 64; i += stride) {
    int reg = i & 3, it = (i >> 2) & 3, jt = (i >> 4) & 3;
    int l = (i >> 6) & 63, h = i >> 12;
    int qi = it * 16 + (l & 15);            // query (column)
    int kj = jt * 16 + (l >> 4) * 4 + reg;  // key (row)
    bfr[i] = tbl[ridx[qi * 64 + kj] * 4 + h];
  }
}

// ---------------------------------------------------------------------------
// fused window attention, register-resident QKV/P (wave = head).
// LDS: XS [64][128] bf16 @0, AO [64][128] bf16 @16384 (separate regions ->
// only 2 barriers).  All lane exchanges + softmax reductions are pure VALU
// (permlane swaps) -> no LDS on the MFMA dependency chain.
// ---------------------------------------------------------------------------
__global__ __launch_bounds__(256) void winattn_kernel(
    const float* __restrict__ x, const float* __restrict__ proj_b,
    const short* __restrict__ wq, const short* __restrict__ wp,
    const float* __restrict__ qb, const float* __restrict__ bfr,
    float* __restrict__ out) {
  __shared__ __align__(16) char lds[32768];
  char* const ao = lds + 16384;

  const int tid = threadIdx.x;
  const int w = tid >> 6;  // wave id == head
  const int l = tid & 63;
  const int llo = l & 15, lhi = l >> 4;

  // XCD-bijective swizzle (8192 % 8 == 0)
  const int bid = blockIdx.x;
  const int wid = (bid & 7) * 1024 + (bid >> 3);
  const int b = wid >> 10;
  const int wy = (wid >> 5) & 31, wx = wid & 31;
  const int y0 = wy * 8, x0 = wx * 8;

  // ---- Phase 0: issue ALL x loads first, then scatter to LDS.
  const float* xb = x + (size_t)b * 128 * 65536;
  f32x4 xv[8];
#pragma unroll
  for (int k = 0; k < 8; ++k) {
    int u = tid + k * 256;
    int c = u >> 4, i = (u >> 1) & 7, j4 = u & 1;
    xv[k] = *(const f32x4*)(xb + (size_t)c * 65536 + (y0 + i) * 256 + x0 + j4 * 4);
  }
#pragma unroll
  for (int k = 0; k < 8; ++k) {
    int u = tid + k * 256;
    int c = u >> 4, i = (u >> 1) & 7, j4 = u & 1;
    int t0 = i * 8 + j4 * 4;
#pragma unroll
    for (int n = 0; n < 4; ++n)  // SWZ depends on t low bits: per-elem addr
      *(short*)(lds + (((t0 + n) * 256 + c * 2) ^ SWZ(t0 + n))) = f2bf(xv[k][n]);
  }
  __syncthreads();

  // ---- Phase 1: QKV GEMM, outputs packed bf16 in registers.
  // g 0,1 = Q tiles (C[o][t]); 2,3 = K tiles (C[o][t]); 4,5 = V tiles (C[t][d])
  unsigned pkq[2][4][2], pkk[2][4][2], pkv[2][4][2];
#pragma unroll
  for (int grp = 0; grp < 2; ++grp) {
    bf16x8 wf[3][4];
    f32x4 qb4[3];
    float bv[3];
#pragma unroll
    for (int gi = 0; gi < 3; ++gi) {
      const int g = grp * 3 + gi;
      const int rowbase = (g >> 1) * 128 + w * 32 + (g & 1) * 16;
#pragma unroll
      for (int ks = 0; ks < 4; ++ks)
        wf[gi][ks] = *(const bf16x8*)(wq + (rowbase + llo) * 128 + ks * 32 + lhi * 8);
      if (g < 4)
        qb4[gi] = *(const f32x4*)(qb + rowbase + lhi * 4);
      else
        bv[gi] = qb[rowbase + llo];
    }
#pragma unroll
    for (int tt = 0; tt < 4; ++tt) {
      bf16x8 xf[4];
      const int t = tt * 16 + llo;
#pragma unroll
      for (int ks = 0; ks < 4; ++ks)
        xf[ks] = *(const bf16x8*)(lds + ((t * 256 + ks * 64 + lhi * 16) ^ SWZ(t)));
#pragma unroll
      for (int gi = 0; gi < 3; ++gi) {
        const int g = grp * 3 + gi;
        f32x4 acc = {0.f, 0.f, 0.f, 0.f};
        if (g < 4) {
#pragma unroll
          for (int ks = 0; ks < 4; ++ks) acc = MFMA(wf[gi][ks], xf[ks], acc);
          unsigned d0 = cvtpk(acc[0] + qb4[gi][0], acc[1] + qb4[gi][1]);
          unsigned d1 = cvtpk(acc[2] + qb4[gi][2], acc[3] + qb4[gi][3]);
          if (g < 2) { pkq[g][tt][0] = d0; pkq[g][tt][1] = d1; }
          else       { pkk[g - 2][tt][0] = d0; pkk[g - 2][tt][1] = d1; }
        } else {
#pragma unroll
          for (int ks = 0; ks < 4; ++ks) acc = MFMA(xf[ks], wf[gi][ks], acc);
          pkv[g - 4][tt][0] = cvtpk(acc[0] + bv[gi], acc[1] + bv[gi]);
          pkv[g - 4][tt][1] = cvtpk(acc[2] + bv[gi], acc[3] + bv[gi]);
        }
      }
    }
  }
  // no barrier: XS has no writers after phase 0; AO is a separate region

  // ---- Build K A-frags and V A-frags; prefetch it=0 bias behind them
  const f32x4* bias4 = (const f32x4*)bfr + ((w * 64 + l) << 4);
  bf16x8 kf[4], va[2][2];
  f32x4 biasreg[4];
#pragma unroll
  for (int jt = 0; jt < 4; ++jt) biasreg[jt] = bias4[jt * 4];  // it = 0
#pragma unroll
  for (int jt = 0; jt < 4; ++jt)
    kf[jt] = xch2(pkk[0][jt][0], pkk[0][jt][1], pkk[1][jt][0], pkk[1][jt][1]);
#pragma unroll
  for (int vt = 0; vt < 2; ++vt)
#pragma unroll
    for (int ks = 0; ks < 2; ++ks)
      va[vt][ks] = xch2(pkv[vt][2 * ks][0], pkv[vt][2 * ks][1],
                        pkv[vt][2 * ks + 1][0], pkv[vt][2 * ks + 1][1]);

  // ---- Phases 2-4 fused, streamed per query tile `it`
#pragma unroll
  for (int it = 0; it < 4; ++it) {
    bf16x8 qf = xch2(pkq[0][it][0], pkq[0][it][1], pkq[1][it][0], pkq[1][it][1]);
    f32x4 dots[4];
    __builtin_amdgcn_s_setprio(1);
#pragma unroll
    for (int jt = 0; jt < 4; ++jt)
      dots[jt] = MFMA(kf[jt], qf, biasreg[jt]);  // bias as accumulator init
    __builtin_amdgcn_s_setprio(0);
    // prefetch next it's bias while softmax runs (hides L2 latency)
    f32x4 biasnext[4];
    if (it < 3) {
#pragma unroll
      for (int jt = 0; jt < 4; ++jt) biasnext[jt] = bias4[jt * 4 + it + 1];
    }
    // softmax over key axis: 16 lane-local values + VALU cross-lane reduce
    float m = dots[0][0];
#pragma unroll
    for (int jt = 0; jt < 4; ++jt)
#pragma unroll
      for (int r = 0; r < 4; ++r) m = fmaxf(m, dots[jt][r]);
    m = redmax16(m);
    m = redmax32(m);
    float p[4][4];
    float s = 0.f;
#pragma unroll
    for (int jt = 0; jt < 4; ++jt)
#pragma unroll
      for (int r = 0; r < 4; ++r) {
        p[jt][r] = __expf(dots[jt][r] - m);
        s += p[jt][r];
      }
    s = redsum16(s);
    s = redsum32(s);
    const float inv = 1.f / s;
    unsigned pk[4][2];
#pragma unroll
    for (int jt = 0; jt < 4; ++jt) {
      pk[jt][0] = cvtpk(p[jt][0], p[jt][1]);
      pk[jt][1] = cvtpk(p[jt][2], p[jt][3]);
    }
    bf16x8 pb0 = xch2(pk[0][0], pk[0][1], pk[1][0], pk[1][1]);
    bf16x8 pb1 = xch2(pk[2][0], pk[2][1], pk[3][0], pk[3][1]);
    // PV: C[d][t] (rows = d, cols = query token)
    f32x4 o0 = {0.f, 0.f, 0.f, 0.f}, o1 = {0.f, 0.f, 0.f, 0.f};
    __builtin_amdgcn_s_setprio(1);
    o0 = MFMA(va[0][0], pb0, o0);
    o0 = MFMA(va[0][1], pb1, o0);
    o1 = MFMA(va[1][0], pb0, o1);
    o1 = MFMA(va[1][1], pb1, o1);
    __builtin_amdgcn_s_setprio(0);
    // normalize + write AO[t][c] (c = head*32 + d), packed b64, swizzled.
    // Full byte address computed BEFORE the XOR.
    const int t = it * 16 + llo;
    const int byte0 = (t * 256 + (w * 32 + lhi * 4) * 2) ^ SWZ(t);
    const int byte1 = (t * 256 + (w * 32 + 16 + lhi * 4) * 2) ^ SWZ(t);
    u32x2 w0, w1;
    w0.x = cvtpk(o0[0] * inv, o0[1] * inv);
    w0.y = cvtpk(o0[2] * inv, o0[3] * inv);
    w1.x = cvtpk(o1[0] * inv, o1[1] * inv);
    w1.y = cvtpk(o1[2] * inv, o1[3] * inv);
    *(u32x2*)(ao + byte0) = w0;
    *(u32x2*)(ao + byte1) = w1;
#pragma unroll
    for (int jt = 0; jt < 4; ++jt) biasreg[jt] = biasnext[jt];
  }

  // ---- Phase 6: proj with C[token][och] (A = AO token rows, B = wp och rows)
  // -> each lane's 4 acc regs = 4 consecutive pixels of one channel ->
  // coalesced f32x4 stores.
  bf16x8 wpf[2][4];
  float pb2[2];
#pragma unroll
  for (int ot = 0; ot < 2; ++ot) {
#pragma unroll
    for (int ks = 0; ks < 4; ++ks)
      wpf[ot][ks] = *(const bf16x8*)(wp + (w * 32 + ot * 16 + llo) * 128 + ks * 32 + lhi * 8);
    pb2[ot] = proj_b[w * 32 + ot * 16 + llo];
  }
  __syncthreads();  // AO complete

  float* ob = out + (size_t)b * 128 * 65536;
#pragma unroll
  for (int it = 0; it < 4; ++it) {
    const int t = it * 16 + llo;
    bf16x8 af[4];
#pragma unroll
    for (int ks = 0; ks < 4; ++ks)
      af[ks] = *(const bf16x8*)(ao + ((t * 256 + ks * 64 + lhi * 16) ^ SWZ(t)));
#pragma unroll
    for (int ot = 0; ot < 2; ++ot) {
      f32x4 acc = {0.f, 0.f, 0.f, 0.f};
      __builtin_amdgcn_s_setprio(1);
#pragma unroll
      for (int ks = 0; ks < 4; ++ks) acc = MFMA(af[ks], wpf[ot][ks], acc);
      __builtin_amdgcn_s_setprio(0);
      // lane holds tokens tq..tq+3 (4 consecutive pixels) of channel ch
      const int ch = w * 32 + ot * 16 + llo;
      const int tq = it * 16 + lhi * 4;
      f32x4 v4 = {acc[0] + pb2[ot], acc[1] + pb2[ot],
                  acc[2] + pb2[ot], acc[3] + pb2[ot]};
      *(f32x4*)(ob + (size_t)ch * 65536 + (y0 + (tq >> 3)) * 256 + x0 + (tq & 7)) = v4;
    }
  }
}

extern "C" void kernel_launch(void* const* d_in, const int* in_sizes, int n_in,
                              void* d_out, int out_size, void* d_ws, size_t ws_size,
                              hipStream_t stream) {
  const float* x = (const float*)d_in[0];
  const float* qkv_w = (const float*)d_in[1];
  const float* qkv_b = (const float*)d_in[2];
  const float* proj_w = (const float*)d_in[3];
  const float* proj_b = (const float*)d_in[4];
  const float* tbl = (const float*)d_in[5];
  const int* ridx = (const int*)d_in[6];
  float* out = (float*)d_out;

  char* ws = (char*)d_ws;
  short* wq = (short*)ws;                    //      0 .. 98304: qkv_w bf16 (Q pre-scaled)
  short* wp = (short*)(ws + 98304);          //  98304 ..131072: proj_w bf16
  float* qb = (float*)(ws + 131072);         // 131072 ..132608: scaled qkv_b f32
  float* bfr = (float*)(ws + 132608);        // 132608 ..198144: bias, transposed frag order

  prep_kernel<<<64, 256, 0, stream>>>(qkv_w, qkv_b, proj_w, tbl, ridx, wq, wp, qb, bfr);
  winattn_kernel<<<8192, 256, 0, stream>>>(x, proj_b, wq, wp, qb, bfr, out);
}